// Round 2
// baseline (307.215 us; speedup 1.0000x reference)
//
#include <hip/hip_runtime.h>
#include <math.h>

#define IN_F   1024
#define NB     256
#define NL     17
#define BATCH_N 16384

// rows per block in the main kernel
#define RPB 8

// ---------------------------------------------------------------------------
// Kernel 1: expm of 4352 4x4 matrices (f64 scaling-and-squaring + Taylor),
// plus global sum of traces (the data-independent logdet term).
// ---------------------------------------------------------------------------
__global__ __launch_bounds__(256) void expm_kernel(const float* __restrict__ vs,
                                                   float* __restrict__ E,
                                                   float* __restrict__ tr_acc) {
    const int m = blockIdx.x * 256 + threadIdx.x;   // 0..4351 (grid is exact)
    const float* v = vs + (size_t)m * 16;
    double A[16], X[16], P[16], T[16];
    #pragma unroll
    for (int i = 0; i < 16; ++i) A[i] = (double)v[i];
    const double tr = A[0] + A[5] + A[10] + A[15];

    // 1-norm (max column abs-sum)
    double n1 = 0.0;
    #pragma unroll
    for (int j = 0; j < 4; ++j) {
        double c = fabs(A[j]) + fabs(A[4 + j]) + fabs(A[8 + j]) + fabs(A[12 + j]);
        n1 = fmax(n1, c);
    }
    int s = 0;
    while (n1 > 0.25 && s < 40) { n1 *= 0.5; ++s; }
    const double sc = ldexp(1.0, -s);
    #pragma unroll
    for (int i = 0; i < 16; ++i) { A[i] *= sc; P[i] = A[i]; X[i] = A[i]; }
    X[0] += 1.0; X[5] += 1.0; X[10] += 1.0; X[15] += 1.0;

    // Taylor terms 2..12 (norm <= 0.25 -> term 12 ~ 1e-16)
    for (int k = 2; k <= 12; ++k) {
        const double invk = 1.0 / (double)k;
        #pragma unroll
        for (int i = 0; i < 4; ++i)
            #pragma unroll
            for (int j = 0; j < 4; ++j)
                T[i * 4 + j] = P[i * 4 + 0] * A[0 + j] + P[i * 4 + 1] * A[4 + j] +
                               P[i * 4 + 2] * A[8 + j] + P[i * 4 + 3] * A[12 + j];
        #pragma unroll
        for (int i = 0; i < 16; ++i) { P[i] = T[i] * invk; X[i] += P[i]; }
    }
    // undo scaling: square s times
    for (int q = 0; q < s; ++q) {
        #pragma unroll
        for (int i = 0; i < 4; ++i)
            #pragma unroll
            for (int j = 0; j < 4; ++j)
                T[i * 4 + j] = X[i * 4 + 0] * X[0 + j] + X[i * 4 + 1] * X[4 + j] +
                               X[i * 4 + 2] * X[8 + j] + X[i * 4 + 3] * X[12 + j];
        #pragma unroll
        for (int i = 0; i < 16; ++i) X[i] = T[i];
    }
    float* e = E + (size_t)m * 16;
    #pragma unroll
    for (int i = 0; i < 16; ++i) e[i] = (float)X[i];

    // wave-reduce traces, one atomic per wave
    float tf = (float)tr;
    #pragma unroll
    for (int off = 32; off > 0; off >>= 1) tf += __shfl_down(tf, off);
    if ((threadIdx.x & 63) == 0) atomicAdd(tr_acc, tf);
}

// ---------------------------------------------------------------------------
// Kernel 2: fused 17-layer flow. One block = RPB rows; thread t owns features
// 4t..4t+3. z lives in registers; LDS used only for the per-layer permutation.
// ---------------------------------------------------------------------------
__global__ __launch_bounds__(256) void flow_kernel(const float* __restrict__ data,
                                                   const float* __restrict__ E,
                                                   const float* __restrict__ bs,
                                                   const int* __restrict__ idxs,
                                                   const float* __restrict__ tr_acc,
                                                   float* __restrict__ out) {
    __shared__ float lds[RPB][IN_F];
    __shared__ float red[RPB][4];
    const int t = threadIdx.x;
    const int row0 = blockIdx.x * RPB;

    float z[RPB][4];
    #pragma unroll
    for (int r = 0; r < RPB; ++r) {
        const float4 v = *(const float4*)(data + (size_t)(row0 + r) * IN_F + 4 * t);
        z[r][0] = v.x; z[r][1] = v.y; z[r][2] = v.z; z[r][3] = v.w;
    }
    float ld[RPB];
    #pragma unroll
    for (int r = 0; r < RPB; ++r) ld[r] = 0.0f;

    for (int l = 0; l < NL; ++l) {
        if (l > 0) {
            // bent identity + logdet partial (all in registers)
            #pragma unroll
            for (int r = 0; r < RPB; ++r) {
                #pragma unroll
                for (int e = 0; e < 4; ++e) {
                    const float zz = z[r][e];
                    const float q = fmaf(zz, zz, 1.0f);
                    const float inv_s = rsqrtf(q);
                    const float sq = q * inv_s;                    // sqrt(z^2+1)
                    ld[r] += __logf(fmaf(zz * 0.5f, inv_s, 1.0f)); // log(z/(2s)+1)
                    z[r][e] = fmaf(sq - 1.0f, 0.5f, zz);
                }
            }
        }
        // per-thread 4x4 block of E for this layer (L2-resident, 16 KB/layer)
        const float* ep = E + ((size_t)l * NB + t) * 16;
        const float4 e0 = *(const float4*)(ep + 0);
        const float4 e1 = *(const float4*)(ep + 4);
        const float4 e2 = *(const float4*)(ep + 8);
        const float4 e3 = *(const float4*)(ep + 12);
        const float4 bv = *(const float4*)(bs + (size_t)l * IN_F + 4 * t);

        #pragma unroll
        for (int r = 0; r < RPB; ++r) {
            float4 y;
            y.x = z[r][0] * e0.x + z[r][1] * e1.x + z[r][2] * e2.x + z[r][3] * e3.x + bv.x;
            y.y = z[r][0] * e0.y + z[r][1] * e1.y + z[r][2] * e2.y + z[r][3] * e3.y + bv.y;
            y.z = z[r][0] * e0.z + z[r][1] * e1.z + z[r][2] * e2.z + z[r][3] * e3.z + bv.z;
            y.w = z[r][0] * e0.w + z[r][1] * e1.w + z[r][2] * e2.w + z[r][3] * e3.w + bv.w;
            *(float4*)(&lds[r][4 * t]) = y;
        }
        __syncthreads();
        const int4 id = *(const int4*)(idxs + (size_t)l * IN_F + 4 * t);
        #pragma unroll
        for (int r = 0; r < RPB; ++r) {
            z[r][0] = lds[r][id.x];
            z[r][1] = lds[r][id.y];
            z[r][2] = lds[r][id.z];
            z[r][3] = lds[r][id.w];
        }
        __syncthreads();
    }

    // write z
    float* out_z = out;
    float* out_ld = out + (size_t)BATCH_N * IN_F;
    #pragma unroll
    for (int r = 0; r < RPB; ++r) {
        float4 v;
        v.x = z[r][0]; v.y = z[r][1]; v.z = z[r][2]; v.w = z[r][3];
        *(float4*)(out_z + (size_t)(row0 + r) * IN_F + 4 * t) = v;
    }

    // per-row logdet reduction: wave shfl then cross-wave via LDS
    const float tr = *tr_acc;
    #pragma unroll
    for (int r = 0; r < RPB; ++r) {
        float p = ld[r];
        #pragma unroll
        for (int off = 32; off > 0; off >>= 1) p += __shfl_down(p, off);
        if ((t & 63) == 0) red[r][t >> 6] = p;
    }
    __syncthreads();
    if (t < RPB) {
        const float ssum = red[t][0] + red[t][1] + red[t][2] + red[t][3];
        out_ld[row0 + t] = -tr - ssum;
    }
}

// ---------------------------------------------------------------------------
extern "C" void kernel_launch(void* const* d_in, const int* in_sizes, int n_in,
                              void* d_out, int out_size, void* d_ws, size_t ws_size,
                              hipStream_t stream) {
    const float* data = (const float*)d_in[0];
    const float* vs   = (const float*)d_in[1];
    const float* bs   = (const float*)d_in[2];
    const int*   idxs = (const int*)d_in[3];

    float* ws     = (float*)d_ws;
    float* tr_acc = ws;        // 1 float accumulator
    float* E      = ws + 16;   // 17*256*16 floats = 272 KB

    hipMemsetAsync(tr_acc, 0, sizeof(float), stream);
    expm_kernel<<<NL, 256, 0, stream>>>(vs, E, tr_acc);
    flow_kernel<<<BATCH_N / RPB, 256, 0, stream>>>(data, E, bs, idxs, tr_acc, (float*)d_out);
}